// Round 1
// baseline (1573.690 us; speedup 1.0000x reference)
//
#include <hip/hip_runtime.h>
#include <hip/hip_bf16.h>

#define T_TOK 4096
#define DDIM  2048
#define FDIM  4096
#define NEXP  8
#define MAXROWS 9216   // T*2 + 8*128 padding
#define MAXMT   72     // MAXROWS/128

typedef __attribute__((ext_vector_type(4))) float f32x4;
typedef __attribute__((ext_vector_type(8))) short bf16x8;

__device__ __forceinline__ unsigned short f2b(float f) {
  union { float f; unsigned u; } c; c.f = f;
  unsigned r = c.u + 0x7FFFu + ((c.u >> 16) & 1u);
  return (unsigned short)(r >> 16);
}

// ---------------- gating: one wave per token ----------------
__global__ void gate_topk(const float* __restrict__ x, const float* __restrict__ gw,
                          int* __restrict__ sel_e, float* __restrict__ sel_w) {
  const int t = blockIdx.x * 4 + (threadIdx.x >> 6);
  const int l = threadIdx.x & 63;
  const float* xr = x + (size_t)t * DDIM;
  float acc[8];
  #pragma unroll
  for (int e = 0; e < 8; ++e) acc[e] = 0.f;
  for (int d = l; d < DDIM; d += 64) {
    const float xv = xr[d];
    const float* g = gw + d * 8;
    #pragma unroll
    for (int e = 0; e < 8; ++e) acc[e] = fmaf(xv, g[e], acc[e]);
  }
  #pragma unroll
  for (int e = 0; e < 8; ++e) {
    float v = acc[e];
    #pragma unroll
    for (int off = 32; off; off >>= 1) v += __shfl_xor(v, off, 64);
    acc[e] = v;
  }
  if (l == 0) {
    int e0 = 0; float v0 = acc[0];
    #pragma unroll
    for (int e = 1; e < 8; ++e) if (acc[e] > v0) { v0 = acc[e]; e0 = e; }
    int e1 = -1; float v1 = -1e30f;
    #pragma unroll
    for (int e = 0; e < 8; ++e) if (e != e0 && acc[e] > v1) { v1 = acc[e]; e1 = e; }
    const float ex = __expf(v1 - v0);
    const float w0 = 1.f / (1.f + ex);
    sel_e[t * 2] = e0; sel_e[t * 2 + 1] = e1;
    sel_w[t * 2] = w0; sel_w[t * 2 + 1] = ex * w0;
  }
}

// ---------------- per-expert lists (single block) ----------------
__global__ void build_lists(const int* __restrict__ sel_e, const float* __restrict__ sel_w,
                            int* __restrict__ cnt, int* __restrict__ base,
                            int* __restrict__ row_token, float* __restrict__ row_gw) {
  __shared__ int c[8], f[8], b[9];
  const int tid = threadIdx.x;
  if (tid < 8) { c[tid] = 0; f[tid] = 0; }
  __syncthreads();
  for (int t = tid; t < T_TOK; t += 256) {
    atomicAdd(&c[sel_e[t * 2]], 1);
    atomicAdd(&c[sel_e[t * 2 + 1]], 1);
  }
  __syncthreads();
  if (tid == 0) {
    int r = 0;
    for (int e = 0; e < 8; ++e) { b[e] = r; r += ((c[e] + 127) >> 7) << 7; }
    b[8] = r;
    for (int e = 0; e < 8; ++e) { cnt[e] = c[e]; base[e] = b[e]; }
    base[8] = r;
  }
  __syncthreads();
  for (int i = tid; i < MAXROWS; i += 256) { row_token[i] = -1; row_gw[i] = 0.f; }
  __syncthreads();
  for (int t = tid; t < T_TOK; t += 256) {
    #pragma unroll
    for (int k = 0; k < 2; ++k) {
      const int e = sel_e[t * 2 + k];
      const int p = b[e] + atomicAdd(&f[e], 1);
      row_token[p] = t; row_gw[p] = sel_w[t * 2 + k];
    }
  }
}

// ---------------- gather x rows -> compact bf16 ----------------
__global__ void gather_x(const float* __restrict__ x, const int* __restrict__ base,
                         const int* __restrict__ row_token, unsigned short* __restrict__ xc) {
  const int i = blockIdx.x;
  if (i >= base[8]) return;
  const int t = row_token[i];
  const int tid = threadIdx.x;
  union { uint4 u; unsigned short s[8]; } o;
  if (t < 0) { o.u.x = 0u; o.u.y = 0u; o.u.z = 0u; o.u.w = 0u; }
  else {
    const float4* src = (const float4*)(x + (size_t)t * DDIM + tid * 8);
    const float4 a = src[0], bb = src[1];
    o.s[0] = f2b(a.x);  o.s[1] = f2b(a.y);  o.s[2] = f2b(a.z);  o.s[3] = f2b(a.w);
    o.s[4] = f2b(bb.x); o.s[5] = f2b(bb.y); o.s[6] = f2b(bb.z); o.s[7] = f2b(bb.w);
  }
  ((uint4*)(xc + (size_t)i * DDIM))[tid] = o.u;
}

// ---------------- GEMM1: hidden = silu(xc@w1[e]) * (xc@w3[e]) ----------------
__global__ void gemm1_kern(const unsigned short* __restrict__ xc,
                           const float* __restrict__ w1,
                           const float* __restrict__ w3,
                           const int* __restrict__ base,
                           unsigned short* __restrict__ hidden) {
  const int m0 = blockIdx.x * 128;
  const int total = base[8];
  if (m0 >= total) return;
  int e = 0;
  #pragma unroll
  for (int q = 1; q < 8; ++q) if (m0 >= base[q]) e = q;
  const int n0 = blockIdx.y * 64;

  const float* B1 = w1 + (size_t)e * DDIM * FDIM + n0;
  const float* B3 = w3 + (size_t)e * DDIM * FDIM + n0;

  __shared__ __align__(16) unsigned short As[128 * 32];
  __shared__ __align__(16) unsigned short Bs1[64 * 32];
  __shared__ __align__(16) unsigned short Bs3[64 * 32];

  const int tid = threadIdx.x;
  const int l = tid & 63;
  const int wid = tid >> 6;
  const int wm = wid >> 1, wn = wid & 1;

  const f32x4 vzero = {0.f, 0.f, 0.f, 0.f};
  f32x4 acc1[4][2], acc3[4][2];
  #pragma unroll
  for (int i = 0; i < 4; ++i)
    #pragma unroll
    for (int j = 0; j < 2; ++j) { acc1[i][j] = vzero; acc3[i][j] = vzero; }

  const int arow = tid >> 1;        // 0..127
  const int ac0 = tid & 1;          // chunks ac0, ac0+2
  const unsigned short* Ag = xc + (size_t)(m0 + arow) * DDIM;

  const int kk = (tid >> 4) * 2;    // 0,2,..,30
  const int n4 = (tid & 15) * 4;    // 0,4,..,60
  const int bchunk = kk >> 3;
  const int bwithin = (kk & 7) * 2;

  const int kc = l >> 4;
  const int lr = l & 15;

  for (int k0 = 0; k0 < DDIM; k0 += 32) {
    __syncthreads();
    // stage A (bf16, XOR-swizzled 16B chunks)
    #pragma unroll
    for (int cc = 0; cc < 2; ++cc) {
      const int c = ac0 + cc * 2;
      uint4 v = *(const uint4*)(Ag + k0 + c * 8);
      const int sc = c ^ (arow & 3);
      *(uint4*)((char*)As + arow * 64 + sc * 16) = v;
    }
    // stage B1 (fp32 -> bf16, transpose to [n][k], swizzled)
    {
      const float* p0 = B1 + (size_t)(k0 + kk) * FDIM;
      const float4 r0 = *(const float4*)(p0 + n4);
      const float4 r1 = *(const float4*)(p0 + FDIM + n4);
      const float a0[4] = {r0.x, r0.y, r0.z, r0.w};
      const float a1[4] = {r1.x, r1.y, r1.z, r1.w};
      #pragma unroll
      for (int j = 0; j < 4; ++j) {
        const int n = n4 + j;
        const unsigned pk = (unsigned)f2b(a0[j]) | ((unsigned)f2b(a1[j]) << 16);
        *(unsigned*)((char*)Bs1 + n * 64 + ((bchunk ^ (n & 3)) * 16) + bwithin) = pk;
      }
    }
    // stage B3
    {
      const float* p0 = B3 + (size_t)(k0 + kk) * FDIM;
      const float4 r0 = *(const float4*)(p0 + n4);
      const float4 r1 = *(const float4*)(p0 + FDIM + n4);
      const float a0[4] = {r0.x, r0.y, r0.z, r0.w};
      const float a1[4] = {r1.x, r1.y, r1.z, r1.w};
      #pragma unroll
      for (int j = 0; j < 4; ++j) {
        const int n = n4 + j;
        const unsigned pk = (unsigned)f2b(a0[j]) | ((unsigned)f2b(a1[j]) << 16);
        *(unsigned*)((char*)Bs3 + n * 64 + ((bchunk ^ (n & 3)) * 16) + bwithin) = pk;
      }
    }
    __syncthreads();
    // compute
    bf16x8 af[4], b1f[2], b3f[2];
    #pragma unroll
    for (int mf = 0; mf < 4; ++mf) {
      const int row = wm * 64 + mf * 16 + lr;
      af[mf] = *(const bf16x8*)((const char*)As + row * 64 + ((kc ^ (row & 3)) * 16));
    }
    #pragma unroll
    for (int nf = 0; nf < 2; ++nf) {
      const int n = wn * 32 + nf * 16 + lr;
      b1f[nf] = *(const bf16x8*)((const char*)Bs1 + n * 64 + ((kc ^ (n & 3)) * 16));
      b3f[nf] = *(const bf16x8*)((const char*)Bs3 + n * 64 + ((kc ^ (n & 3)) * 16));
    }
    #pragma unroll
    for (int mf = 0; mf < 4; ++mf)
      #pragma unroll
      for (int nf = 0; nf < 2; ++nf) {
        acc1[mf][nf] = __builtin_amdgcn_mfma_f32_16x16x32_bf16(af[mf], b1f[nf], acc1[mf][nf], 0, 0, 0);
        acc3[mf][nf] = __builtin_amdgcn_mfma_f32_16x16x32_bf16(af[mf], b3f[nf], acc3[mf][nf], 0, 0, 0);
      }
  }
  // epilogue: silu(c1)*c3 -> bf16 hidden
  #pragma unroll
  for (int mf = 0; mf < 4; ++mf)
    #pragma unroll
    for (int nf = 0; nf < 2; ++nf)
      #pragma unroll
      for (int rr = 0; rr < 4; ++rr) {
        const int row = m0 + wm * 64 + mf * 16 + (l >> 4) * 4 + rr;
        const int col = n0 + wn * 32 + nf * 16 + lr;
        const float c1 = acc1[mf][nf][rr];
        const float c3 = acc3[mf][nf][rr];
        const float v = (c1 / (1.f + __expf(-c1))) * c3;
        hidden[(size_t)row * FDIM + col] = f2b(v);
      }
}

// ---------------- GEMM2: out[tok] += gw * (hidden @ w2[e]) ----------------
__global__ void gemm2_kern(const unsigned short* __restrict__ hidden,
                           const float* __restrict__ w2,
                           const int* __restrict__ base,
                           const int* __restrict__ row_token,
                           const float* __restrict__ row_gw,
                           float* __restrict__ out) {
  const int m0 = blockIdx.x * 128;
  const int total = base[8];
  if (m0 >= total) return;
  int e = 0;
  #pragma unroll
  for (int q = 1; q < 8; ++q) if (m0 >= base[q]) e = q;
  const int n0 = blockIdx.y * 64;

  const float* B2 = w2 + (size_t)e * FDIM * DDIM + n0;

  __shared__ __align__(16) unsigned short As[128 * 32];
  __shared__ __align__(16) unsigned short Bs[64 * 32];

  const int tid = threadIdx.x;
  const int l = tid & 63;
  const int wid = tid >> 6;
  const int wm = wid >> 1, wn = wid & 1;

  const f32x4 vzero = {0.f, 0.f, 0.f, 0.f};
  f32x4 acc[4][2];
  #pragma unroll
  for (int i = 0; i < 4; ++i)
    #pragma unroll
    for (int j = 0; j < 2; ++j) acc[i][j] = vzero;

  const int arow = tid >> 1;
  const int ac0 = tid & 1;
  const unsigned short* Ag = hidden + (size_t)(m0 + arow) * FDIM;

  const int kk = (tid >> 4) * 2;
  const int n4 = (tid & 15) * 4;
  const int bchunk = kk >> 3;
  const int bwithin = (kk & 7) * 2;

  const int kc = l >> 4;
  const int lr = l & 15;

  for (int k0 = 0; k0 < FDIM; k0 += 32) {
    __syncthreads();
    #pragma unroll
    for (int cc = 0; cc < 2; ++cc) {
      const int c = ac0 + cc * 2;
      uint4 v = *(const uint4*)(Ag + k0 + c * 8);
      const int sc = c ^ (arow & 3);
      *(uint4*)((char*)As + arow * 64 + sc * 16) = v;
    }
    {
      const float* p0 = B2 + (size_t)(k0 + kk) * DDIM;
      const float4 r0 = *(const float4*)(p0 + n4);
      const float4 r1 = *(const float4*)(p0 + DDIM + n4);
      const float a0[4] = {r0.x, r0.y, r0.z, r0.w};
      const float a1[4] = {r1.x, r1.y, r1.z, r1.w};
      #pragma unroll
      for (int j = 0; j < 4; ++j) {
        const int n = n4 + j;
        const unsigned pk = (unsigned)f2b(a0[j]) | ((unsigned)f2b(a1[j]) << 16);
        *(unsigned*)((char*)Bs + n * 64 + ((bchunk ^ (n & 3)) * 16) + bwithin) = pk;
      }
    }
    __syncthreads();
    bf16x8 af[4], bf[2];
    #pragma unroll
    for (int mf = 0; mf < 4; ++mf) {
      const int row = wm * 64 + mf * 16 + lr;
      af[mf] = *(const bf16x8*)((const char*)As + row * 64 + ((kc ^ (row & 3)) * 16));
    }
    #pragma unroll
    for (int nf = 0; nf < 2; ++nf) {
      const int n = wn * 32 + nf * 16 + lr;
      bf[nf] = *(const bf16x8*)((const char*)Bs + n * 64 + ((kc ^ (n & 3)) * 16));
    }
    #pragma unroll
    for (int mf = 0; mf < 4; ++mf)
      #pragma unroll
      for (int nf = 0; nf < 2; ++nf)
        acc[mf][nf] = __builtin_amdgcn_mfma_f32_16x16x32_bf16(af[mf], bf[nf], acc[mf][nf], 0, 0, 0);
  }
  // epilogue: weighted scatter into out
  #pragma unroll
  for (int mf = 0; mf < 4; ++mf)
    #pragma unroll
    for (int nf = 0; nf < 2; ++nf)
      #pragma unroll
      for (int rr = 0; rr < 4; ++rr) {
        const int row = m0 + wm * 64 + mf * 16 + (l >> 4) * 4 + rr;
        const int col = n0 + wn * 32 + nf * 16 + lr;
        const int tok = row_token[row];
        if (tok >= 0) {
          atomicAdd(out + (size_t)tok * DDIM + col, row_gw[row] * acc[mf][nf][rr]);
        }
      }
}

// ---------------- launch ----------------
// ws layout (bytes)
#define OFF_CNT   0u
#define OFF_BASE  64u
#define OFF_SELE  256u          // 4096*2 int
#define OFF_SELW  33024u        // 4096*2 float
#define OFF_RTOK  65792u        // 9216 int
#define OFF_RGW   102656u       // 9216 float
#define OFF_XC    139520u       // 9216*2048 bf16
#define OFF_HID   37888256u     // 9216*4096 bf16  (total ~108 MB)

extern "C" void kernel_launch(void* const* d_in, const int* in_sizes, int n_in,
                              void* d_out, int out_size, void* d_ws, size_t ws_size,
                              hipStream_t stream) {
  const float* x  = (const float*)d_in[0];
  const float* gw = (const float*)d_in[1];
  const float* w1 = (const float*)d_in[2];
  const float* w3 = (const float*)d_in[3];
  const float* w2 = (const float*)d_in[4];
  float* out = (float*)d_out;
  char* ws = (char*)d_ws;

  int*   cnt   = (int*)(ws + OFF_CNT);
  int*   base  = (int*)(ws + OFF_BASE);
  int*   sel_e = (int*)(ws + OFF_SELE);
  float* sel_w = (float*)(ws + OFF_SELW);
  int*   rtok  = (int*)(ws + OFF_RTOK);
  float* rgw   = (float*)(ws + OFF_RGW);
  unsigned short* xc  = (unsigned short*)(ws + OFF_XC);
  unsigned short* hid = (unsigned short*)(ws + OFF_HID);

  hipMemsetAsync(d_out, 0, (size_t)T_TOK * DDIM * sizeof(float), stream);
  gate_topk<<<T_TOK / 4, 256, 0, stream>>>(x, gw, sel_e, sel_w);
  build_lists<<<1, 256, 0, stream>>>(sel_e, sel_w, cnt, base, rtok, rgw);
  gather_x<<<MAXROWS, 256, 0, stream>>>(x, base, rtok, xc);
  gemm1_kern<<<dim3(MAXMT, FDIM / 64), 256, 0, stream>>>(xc, w1, w3, base, hid);
  gemm2_kern<<<dim3(MAXMT, DDIM / 64), 256, 0, stream>>>(hid, w2, base, rtok, rgw, out);
}

// Round 2
// 1020.421 us; speedup vs baseline: 1.5422x; 1.5422x over previous
//
#include <hip/hip_runtime.h>
#include <hip/hip_bf16.h>

#define T_TOK 4096
#define DDIM  2048
#define FDIM  4096
#define NEXP  8
#define MAXROWS 9216   // T*2 + 8*128 padding
#define MAXMT   72     // MAXROWS/128

typedef __attribute__((ext_vector_type(4))) float f32x4;
typedef __attribute__((ext_vector_type(8))) short bf16x8;

__device__ __forceinline__ unsigned short f2b(float f) {
  union { float f; unsigned u; } c; c.f = f;
  unsigned r = c.u + 0x7FFFu + ((c.u >> 16) & 1u);
  return (unsigned short)(r >> 16);
}

// async global->LDS, 16B per lane; LDS dest must be wave-uniform base (+lane*16 implicit)
__device__ __forceinline__ void gload_lds16(const void* g, void* l) {
  __builtin_amdgcn_global_load_lds((__attribute__((address_space(1))) void*)(g),
                                   (__attribute__((address_space(3))) void*)(l),
                                   16, 0, 0);
}

// ---------------- gating: one wave per token ----------------
__global__ void gate_topk(const float* __restrict__ x, const float* __restrict__ gw,
                          int* __restrict__ sel_e, float* __restrict__ sel_w) {
  const int t = blockIdx.x * 4 + (threadIdx.x >> 6);
  const int l = threadIdx.x & 63;
  const float* xr = x + (size_t)t * DDIM;
  float acc[8];
  #pragma unroll
  for (int e = 0; e < 8; ++e) acc[e] = 0.f;
  for (int d = l; d < DDIM; d += 64) {
    const float xv = xr[d];
    const float* g = gw + d * 8;
    #pragma unroll
    for (int e = 0; e < 8; ++e) acc[e] = fmaf(xv, g[e], acc[e]);
  }
  #pragma unroll
  for (int e = 0; e < 8; ++e) {
    float v = acc[e];
    #pragma unroll
    for (int off = 32; off; off >>= 1) v += __shfl_xor(v, off, 64);
    acc[e] = v;
  }
  if (l == 0) {
    int e0 = 0; float v0 = acc[0];
    #pragma unroll
    for (int e = 1; e < 8; ++e) if (acc[e] > v0) { v0 = acc[e]; e0 = e; }
    int e1 = -1; float v1 = -1e30f;
    #pragma unroll
    for (int e = 0; e < 8; ++e) if (e != e0 && acc[e] > v1) { v1 = acc[e]; e1 = e; }
    const float ex = __expf(v1 - v0);
    const float w0 = 1.f / (1.f + ex);
    sel_e[t * 2] = e0; sel_e[t * 2 + 1] = e1;
    sel_w[t * 2] = w0; sel_w[t * 2 + 1] = ex * w0;
  }
}

// ---------------- per-expert lists (single block) ----------------
__global__ void build_lists(const int* __restrict__ sel_e, const float* __restrict__ sel_w,
                            int* __restrict__ cnt, int* __restrict__ base,
                            int* __restrict__ row_token, float* __restrict__ row_gw) {
  __shared__ int c[8], f[8], b[9];
  const int tid = threadIdx.x;
  if (tid < 8) { c[tid] = 0; f[tid] = 0; }
  __syncthreads();
  for (int t = tid; t < T_TOK; t += 256) {
    atomicAdd(&c[sel_e[t * 2]], 1);
    atomicAdd(&c[sel_e[t * 2 + 1]], 1);
  }
  __syncthreads();
  if (tid == 0) {
    int r = 0;
    for (int e = 0; e < 8; ++e) { b[e] = r; r += ((c[e] + 127) >> 7) << 7; }
    b[8] = r;
    for (int e = 0; e < 8; ++e) { cnt[e] = c[e]; base[e] = b[e]; }
    base[8] = r;
  }
  __syncthreads();
  for (int i = tid; i < MAXROWS; i += 256) { row_token[i] = -1; row_gw[i] = 0.f; }
  __syncthreads();
  for (int t = tid; t < T_TOK; t += 256) {
    #pragma unroll
    for (int k = 0; k < 2; ++k) {
      const int e = sel_e[t * 2 + k];
      const int p = b[e] + atomicAdd(&f[e], 1);
      row_token[p] = t; row_gw[p] = sel_w[t * 2 + k];
    }
  }
}

// ---------------- gather x rows -> compact bf16 ----------------
__global__ void gather_x(const float* __restrict__ x, const int* __restrict__ base,
                         const int* __restrict__ row_token, unsigned short* __restrict__ xc) {
  const int i = blockIdx.x;
  if (i >= base[8]) return;
  const int t = row_token[i];
  const int tid = threadIdx.x;
  union { uint4 u; unsigned short s[8]; } o;
  if (t < 0) { o.u.x = 0u; o.u.y = 0u; o.u.z = 0u; o.u.w = 0u; }
  else {
    const float4* src = (const float4*)(x + (size_t)t * DDIM + tid * 8);
    const float4 a = src[0], bb = src[1];
    o.s[0] = f2b(a.x);  o.s[1] = f2b(a.y);  o.s[2] = f2b(a.z);  o.s[3] = f2b(a.w);
    o.s[4] = f2b(bb.x); o.s[5] = f2b(bb.y); o.s[6] = f2b(bb.z); o.s[7] = f2b(bb.w);
  }
  ((uint4*)(xc + (size_t)i * DDIM))[tid] = o.u;
}

// ---------------- transpose + fp32->bf16 convert ----------------
// src: [e][R][C] fp32.  dst: per-expert rows = C*rowMul, ld = R (bf16).
// dst row index = rowMul*c + rowAdd  (rowMul=2 interleaves w1/w3).
__global__ void conv_t(const float* __restrict__ src, unsigned short* __restrict__ dst,
                       int R, int C, int rowMul, int rowAdd) {
  const int e = blockIdx.z;
  const int r0 = blockIdx.x * 64, c0 = blockIdx.y * 64;
  const float* s = src + (size_t)e * R * C + (size_t)r0 * C + c0;
  unsigned short* d = dst + (size_t)e * R * C * rowMul;
  __shared__ unsigned short T[64][68];
  const int t = threadIdx.x;
  {
    const int i = t >> 2, jb = (t & 3) * 16;
    #pragma unroll
    for (int k2 = 0; k2 < 4; ++k2) {
      const float4 v = *(const float4*)(s + (size_t)i * C + jb + k2 * 4);
      uint2 uu;
      uu.x = (unsigned)f2b(v.x) | ((unsigned)f2b(v.y) << 16);
      uu.y = (unsigned)f2b(v.z) | ((unsigned)f2b(v.w) << 16);
      *(uint2*)&T[i][jb + k2 * 4] = uu;
    }
  }
  __syncthreads();
  {
    const int j = t >> 2, ib = (t & 3) * 16;
    union { uint4 q[2]; unsigned short s16[16]; } pk;
    #pragma unroll
    for (int i = 0; i < 16; ++i) pk.s16[i] = T[ib + i][j];
    unsigned short* drow = d + (size_t)(rowMul * (c0 + j) + rowAdd) * R + r0 + ib;
    *(uint4*)drow = pk.q[0];
    *(uint4*)(drow + 8) = pk.q[1];
  }
}

// ---------------- unified grouped GEMM (128x128 tile, BK=64, 4 waves) ----------------
// MODE 0: A=xc[M][2048], B=w13t[e][8192][2048]; epilogue silu(even)*odd -> hid bf16
// MODE 1: A=hid[M][4096], B=w2t[e][2048][4096]; epilogue atomic scatter * gate weight
template<int MODE>
__global__ void moe_gemm(const unsigned short* __restrict__ A,
                         const unsigned short* __restrict__ B,
                         const int* __restrict__ base,
                         const int* __restrict__ rtok, const float* __restrict__ rgw,
                         unsigned short* __restrict__ hid, float* __restrict__ out) {
  constexpr int KDIM = MODE ? FDIM : DDIM;      // 4096 : 2048
  constexpr int NDIM = MODE ? DDIM : 2 * FDIM;  // 2048 : 8192
  const int m0 = blockIdx.x * 128;
  if (m0 >= base[8]) return;
  int e = 0;
  #pragma unroll
  for (int q = 1; q < 8; ++q) if (m0 >= base[q]) e = q;
  const int n0 = blockIdx.y * 128;
  const unsigned short* Bp = B + (size_t)e * NDIM * KDIM;

  __shared__ __align__(16) unsigned short As[128 * 64];
  __shared__ __align__(16) unsigned short Bs[128 * 64];

  const int tid = threadIdx.x;
  const int l = tid & 63;
  const int w = tid >> 6;
  const int wm = w >> 1, wn = w & 1;
  const int lr = l & 15, kc = l >> 4;

  const f32x4 vzero = {0.f, 0.f, 0.f, 0.f};
  f32x4 acc[4][4];
  #pragma unroll
  for (int i = 0; i < 4; ++i)
    #pragma unroll
    for (int j = 0; j < 4; ++j) acc[i][j] = vzero;

  // staging: wave w fills LDS bytes [w*4KB, (w+1)*4KB) in 4 issues of 1KB
  // linear LDS slot (row, c): row = off>>7, c = (off>>4)&7; holds global chunk c^(row&7)
  const int srow = w * 32 + (l >> 3);
  const int sc = l & 7;
  const unsigned short* Arow = A + (size_t)(m0 + srow) * KDIM;
  const unsigned short* Brow = Bp + (size_t)(n0 + srow) * KDIM;

  for (int k0 = 0; k0 < KDIM; k0 += 64) {
    #pragma unroll
    for (int q = 0; q < 4; ++q) {
      const int r = srow + q * 8;
      const int cg = (sc ^ (r & 7)) << 3;
      gload_lds16(Arow + (size_t)q * 8 * KDIM + k0 + cg,
                  (unsigned short*)As + w * 2048 + q * 512);
      gload_lds16(Brow + (size_t)q * 8 * KDIM + k0 + cg,
                  (unsigned short*)Bs + w * 2048 + q * 512);
    }
    __syncthreads();   // drains vmcnt -> staged data visible to all waves
    #pragma unroll
    for (int ks = 0; ks < 2; ++ks) {
      bf16x8 af[4], bfr[4];
      #pragma unroll
      for (int mf = 0; mf < 4; ++mf) {
        const int r = wm * 64 + mf * 16 + lr;
        const int c = (ks * 4 + kc) ^ (r & 7);
        af[mf] = *(const bf16x8*)((const char*)As + r * 128 + c * 16);
      }
      #pragma unroll
      for (int nf = 0; nf < 4; ++nf) {
        const int n = wn * 64 + nf * 16 + lr;
        const int c = (ks * 4 + kc) ^ (n & 7);
        bfr[nf] = *(const bf16x8*)((const char*)Bs + n * 128 + c * 16);
      }
      #pragma unroll
      for (int mf = 0; mf < 4; ++mf)
        #pragma unroll
        for (int nf = 0; nf < 4; ++nf)
          acc[mf][nf] = __builtin_amdgcn_mfma_f32_16x16x32_bf16(af[mf], bfr[nf], acc[mf][nf], 0, 0, 0);
    }
    __syncthreads();   // all waves done reading before next stage overwrites
  }

  if (MODE == 0) {
    // cols are interleaved: even = h (w1), odd = g (w3). out col = global_col/2.
    const int fbase = (n0 >> 1) + wn * 32;
    #pragma unroll
    for (int mf = 0; mf < 4; ++mf) {
      const int row = m0 + wm * 64 + mf * 16 + (kc << 2);
      #pragma unroll
      for (int nf = 0; nf < 4; ++nf)
        #pragma unroll
        for (int rr = 0; rr < 4; ++rr) {
          const float v = acc[mf][nf][rr];
          const float o = __shfl_xor(v, 1, 64);
          const float h = (l & 1) ? o : v;
          const float g = (l & 1) ? v : o;
          const float res = (h / (1.f + __expf(-h))) * g;
          const float vc = __shfl(res, (l & 48) | ((l & 7) << 1), 64);
          if (lr < 8)
            hid[(size_t)(row + rr) * FDIM + fbase + nf * 8 + (l & 7)] = f2b(vc);
        }
    }
  } else {
    #pragma unroll
    for (int mf = 0; mf < 4; ++mf) {
      const int row = m0 + wm * 64 + mf * 16 + (kc << 2);
      #pragma unroll
      for (int rr = 0; rr < 4; ++rr) {
        const int tok = rtok[row + rr];
        if (tok < 0) continue;
        const float gwt = rgw[row + rr];
        float* orow = out + (size_t)tok * DDIM;
        #pragma unroll
        for (int nf = 0; nf < 4; ++nf) {
          const int col = n0 + wn * 64 + nf * 16 + lr;
          atomicAdd(orow + col, gwt * acc[mf][nf][rr]);
        }
      }
    }
  }
}

// ---------------- launch ----------------
// ws layout (bytes)
#define OFF_CNT   0u
#define OFF_BASE  64u
#define OFF_SELE  4096u
#define OFF_SELW  36864u
#define OFF_RTOK  69632u
#define OFF_RGW   106496u
#define OFF_XC    1048576u      // 9216*2048 bf16 = 37748736
#define OFF_HID   38797312u     // 9216*4096 bf16 = 75497472
#define OFF_WBUF  114294784u    // 8*8192*2048 bf16 = 268435456 -> end ~365 MB

extern "C" void kernel_launch(void* const* d_in, const int* in_sizes, int n_in,
                              void* d_out, int out_size, void* d_ws, size_t ws_size,
                              hipStream_t stream) {
  const float* x  = (const float*)d_in[0];
  const float* gw = (const float*)d_in[1];
  const float* w1 = (const float*)d_in[2];
  const float* w3 = (const float*)d_in[3];
  const float* w2 = (const float*)d_in[4];
  float* out = (float*)d_out;
  char* ws = (char*)d_ws;

  int*   cnt   = (int*)(ws + OFF_CNT);
  int*   base  = (int*)(ws + OFF_BASE);
  int*   sel_e = (int*)(ws + OFF_SELE);
  float* sel_w = (float*)(ws + OFF_SELW);
  int*   rtok  = (int*)(ws + OFF_RTOK);
  float* rgw   = (float*)(ws + OFF_RGW);
  unsigned short* xc   = (unsigned short*)(ws + OFF_XC);
  unsigned short* hid  = (unsigned short*)(ws + OFF_HID);
  unsigned short* wbuf = (unsigned short*)(ws + OFF_WBUF);

  hipMemsetAsync(d_out, 0, (size_t)T_TOK * DDIM * sizeof(float), stream);
  gate_topk<<<T_TOK / 4, 256, 0, stream>>>(x, gw, sel_e, sel_w);
  build_lists<<<1, 256, 0, stream>>>(sel_e, sel_w, cnt, base, rtok, rgw);
  gather_x<<<MAXROWS, 256, 0, stream>>>(x, base, rtok, xc);
  // w13t[e][8192][2048]: even rows = w1 cols, odd rows = w3 cols
  conv_t<<<dim3(32, 64, 8), 256, 0, stream>>>(w1, wbuf, DDIM, FDIM, 2, 0);
  conv_t<<<dim3(32, 64, 8), 256, 0, stream>>>(w3, wbuf, DDIM, FDIM, 2, 1);
  moe_gemm<0><<<dim3(MAXMT, 64), 256, 0, stream>>>(xc, wbuf, base, rtok, rgw, hid, nullptr);
  // reuse wbuf for w2t[e][2048][4096]
  conv_t<<<dim3(64, 32, 8), 256, 0, stream>>>(w2, wbuf, FDIM, DDIM, 1, 0);
  moe_gemm<1><<<dim3(MAXMT, 16), 256, 0, stream>>>(hid, wbuf, base, rtok, rgw, nullptr, out);
}

// Round 3
// 941.487 us; speedup vs baseline: 1.6715x; 1.0838x over previous
//
#include <hip/hip_runtime.h>
#include <hip/hip_bf16.h>

#define T_TOK 4096
#define DDIM  2048
#define FDIM  4096
#define NEXP  8
#define MAXROWS 9216   // T*2 + 8*128 padding
#define MAXMT   72     // MAXROWS/128

typedef __attribute__((ext_vector_type(4))) float f32x4;
typedef __attribute__((ext_vector_type(8))) short bf16x8;

__device__ __forceinline__ unsigned short f2b(float f) {
  union { float f; unsigned u; } c; c.f = f;
  unsigned r = c.u + 0x7FFFu + ((c.u >> 16) & 1u);
  return (unsigned short)(r >> 16);
}

// async global->LDS, 16B per lane; LDS dest must be wave-uniform base (+lane*16 implicit)
__device__ __forceinline__ void gload_lds16(const void* g, void* l) {
  __builtin_amdgcn_global_load_lds((__attribute__((address_space(1))) void*)(g),
                                   (__attribute__((address_space(3))) void*)(l),
                                   16, 0, 0);
}

// ---------------- gating: one wave per token ----------------
__global__ void gate_topk(const float* __restrict__ x, const float* __restrict__ gw,
                          int* __restrict__ sel_e, float* __restrict__ sel_w) {
  const int t = blockIdx.x * 4 + (threadIdx.x >> 6);
  const int l = threadIdx.x & 63;
  const float* xr = x + (size_t)t * DDIM;
  float acc[8];
  #pragma unroll
  for (int e = 0; e < 8; ++e) acc[e] = 0.f;
  for (int d = l; d < DDIM; d += 64) {
    const float xv = xr[d];
    const float* g = gw + d * 8;
    #pragma unroll
    for (int e = 0; e < 8; ++e) acc[e] = fmaf(xv, g[e], acc[e]);
  }
  #pragma unroll
  for (int e = 0; e < 8; ++e) {
    float v = acc[e];
    #pragma unroll
    for (int off = 32; off; off >>= 1) v += __shfl_xor(v, off, 64);
    acc[e] = v;
  }
  if (l == 0) {
    int e0 = 0; float v0 = acc[0];
    #pragma unroll
    for (int e = 1; e < 8; ++e) if (acc[e] > v0) { v0 = acc[e]; e0 = e; }
    int e1 = -1; float v1 = -1e30f;
    #pragma unroll
    for (int e = 0; e < 8; ++e) if (e != e0 && acc[e] > v1) { v1 = acc[e]; e1 = e; }
    const float ex = __expf(v1 - v0);
    const float w0 = 1.f / (1.f + ex);
    sel_e[t * 2] = e0; sel_e[t * 2 + 1] = e1;
    sel_w[t * 2] = w0; sel_w[t * 2 + 1] = ex * w0;
  }
}

// ---------------- per-expert lists (single block) ----------------
__global__ void build_lists(const int* __restrict__ sel_e, const float* __restrict__ sel_w,
                            int* __restrict__ cnt, int* __restrict__ base,
                            int* __restrict__ row_token, float* __restrict__ row_gw) {
  __shared__ int c[8], f[8], b[9];
  const int tid = threadIdx.x;
  if (tid < 8) { c[tid] = 0; f[tid] = 0; }
  __syncthreads();
  for (int t = tid; t < T_TOK; t += 256) {
    atomicAdd(&c[sel_e[t * 2]], 1);
    atomicAdd(&c[sel_e[t * 2 + 1]], 1);
  }
  __syncthreads();
  if (tid == 0) {
    int r = 0;
    for (int e = 0; e < 8; ++e) { b[e] = r; r += ((c[e] + 127) >> 7) << 7; }
    b[8] = r;
    for (int e = 0; e < 8; ++e) { cnt[e] = c[e]; base[e] = b[e]; }
    base[8] = r;
  }
  __syncthreads();
  for (int i = tid; i < MAXROWS; i += 256) { row_token[i] = -1; row_gw[i] = 0.f; }
  __syncthreads();
  for (int t = tid; t < T_TOK; t += 256) {
    #pragma unroll
    for (int k = 0; k < 2; ++k) {
      const int e = sel_e[t * 2 + k];
      const int p = b[e] + atomicAdd(&f[e], 1);
      row_token[p] = t; row_gw[p] = sel_w[t * 2 + k];
    }
  }
}

// ---------------- gather x rows -> compact bf16 ----------------
__global__ void gather_x(const float* __restrict__ x, const int* __restrict__ base,
                         const int* __restrict__ row_token, unsigned short* __restrict__ xc) {
  const int i = blockIdx.x;
  if (i >= base[8]) return;
  const int t = row_token[i];
  const int tid = threadIdx.x;
  union { uint4 u; unsigned short s[8]; } o;
  if (t < 0) { o.u.x = 0u; o.u.y = 0u; o.u.z = 0u; o.u.w = 0u; }
  else {
    const float4* src = (const float4*)(x + (size_t)t * DDIM + tid * 8);
    const float4 a = src[0], bb = src[1];
    o.s[0] = f2b(a.x);  o.s[1] = f2b(a.y);  o.s[2] = f2b(a.z);  o.s[3] = f2b(a.w);
    o.s[4] = f2b(bb.x); o.s[5] = f2b(bb.y); o.s[6] = f2b(bb.z); o.s[7] = f2b(bb.w);
  }
  ((uint4*)(xc + (size_t)i * DDIM))[tid] = o.u;
}

// ---------------- transpose + fp32->bf16 convert ----------------
// src: [e][R][C] fp32.  dst: per-expert rows = C*rowMul, ld = R (bf16).
// dst row index = rowMul*c + rowAdd  (rowMul=2 interleaves w1/w3).
__global__ void conv_t(const float* __restrict__ src, unsigned short* __restrict__ dst,
                       int R, int C, int rowMul, int rowAdd) {
  const int e = blockIdx.z;
  const int r0 = blockIdx.x * 64, c0 = blockIdx.y * 64;
  const float* s = src + (size_t)e * R * C + (size_t)r0 * C + c0;
  unsigned short* d = dst + (size_t)e * R * C * rowMul;
  __shared__ unsigned short T[64][68];
  const int t = threadIdx.x;
  {
    const int i = t >> 2, jb = (t & 3) * 16;
    #pragma unroll
    for (int k2 = 0; k2 < 4; ++k2) {
      const float4 v = *(const float4*)(s + (size_t)i * C + jb + k2 * 4);
      uint2 uu;
      uu.x = (unsigned)f2b(v.x) | ((unsigned)f2b(v.y) << 16);
      uu.y = (unsigned)f2b(v.z) | ((unsigned)f2b(v.w) << 16);
      *(uint2*)&T[i][jb + k2 * 4] = uu;
    }
  }
  __syncthreads();
  {
    const int j = t >> 2, ib = (t & 3) * 16;
    union { uint4 q[2]; unsigned short s16[16]; } pk;
    #pragma unroll
    for (int i = 0; i < 16; ++i) pk.s16[i] = T[ib + i][j];
    unsigned short* drow = d + (size_t)(rowMul * (c0 + j) + rowAdd) * R + r0 + ib;
    *(uint4*)drow = pk.q[0];
    *(uint4*)(drow + 8) = pk.q[1];
  }
}

// ---------------- unified grouped GEMM (128x128 tile, BK=64, 4 waves) ----------------
// 1D grid + bijective XCD-chunk swizzle: each XCD gets a contiguous run of the
// m-fast ordering, so all m-tiles sharing an (e,n0) B-panel execute on ONE XCD
// and the panel is read from HBM once, then L2-hit. Grid size must be %8==0.
// MODE 0: A=xc[M][2048], B=w13t[e][8192][2048]; epilogue silu(even)*odd -> hid bf16
// MODE 1: A=hid[M][4096], B=w2t[e][2048][4096]; epilogue atomic scatter * gate weight
template<int MODE>
__global__ void moe_gemm(const unsigned short* __restrict__ A,
                         const unsigned short* __restrict__ B,
                         const int* __restrict__ base,
                         const int* __restrict__ rtok, const float* __restrict__ rgw,
                         unsigned short* __restrict__ hid, float* __restrict__ out) {
  constexpr int KDIM = MODE ? FDIM : DDIM;      // 4096 : 2048
  constexpr int NDIM = MODE ? DDIM : 2 * FDIM;  // 2048 : 8192

  // XCD-aware bijective remap (T1): nwg % 8 == 0 guaranteed by launch config.
  const int nwg = gridDim.x;
  const int q8 = nwg >> 3;
  const int bid = blockIdx.x;
  const int swz = (bid & 7) * q8 + (bid >> 3);
  const int mt = swz % MAXMT;        // m-fast: consecutive swz share the B-panel
  const int nt = swz / MAXMT;

  const int m0 = mt * 128;
  if (m0 >= base[8]) return;
  int e = 0;
  #pragma unroll
  for (int qq = 1; qq < 8; ++qq) if (m0 >= base[qq]) e = qq;
  const int n0 = nt * 128;
  const unsigned short* Bp = B + (size_t)e * NDIM * KDIM;

  __shared__ __align__(16) unsigned short As[128 * 64];
  __shared__ __align__(16) unsigned short Bs[128 * 64];

  const int tid = threadIdx.x;
  const int l = tid & 63;
  const int w = tid >> 6;
  const int wm = w >> 1, wn = w & 1;
  const int lr = l & 15, kc = l >> 4;

  const f32x4 vzero = {0.f, 0.f, 0.f, 0.f};
  f32x4 acc[4][4];
  #pragma unroll
  for (int i = 0; i < 4; ++i)
    #pragma unroll
    for (int j = 0; j < 4; ++j) acc[i][j] = vzero;

  // staging: wave w fills LDS bytes [w*4KB, (w+1)*4KB) in 4 issues of 1KB
  // linear LDS slot (row, c): row = off>>7, c = (off>>4)&7; holds global chunk c^(row&7)
  const int srow = w * 32 + (l >> 3);
  const int sc = l & 7;
  const unsigned short* Arow = A + (size_t)(m0 + srow) * KDIM;
  const unsigned short* Brow = Bp + (size_t)(n0 + srow) * KDIM;

  for (int k0 = 0; k0 < KDIM; k0 += 64) {
    #pragma unroll
    for (int qq = 0; qq < 4; ++qq) {
      const int r = srow + qq * 8;
      const int cg = (sc ^ (r & 7)) << 3;
      gload_lds16(Arow + (size_t)qq * 8 * KDIM + k0 + cg,
                  (unsigned short*)As + w * 2048 + qq * 512);
      gload_lds16(Brow + (size_t)qq * 8 * KDIM + k0 + cg,
                  (unsigned short*)Bs + w * 2048 + qq * 512);
    }
    __syncthreads();   // drains vmcnt -> staged data visible to all waves
    #pragma unroll
    for (int ks = 0; ks < 2; ++ks) {
      bf16x8 af[4], bfr[4];
      #pragma unroll
      for (int mf = 0; mf < 4; ++mf) {
        const int r = wm * 64 + mf * 16 + lr;
        const int c = (ks * 4 + kc) ^ (r & 7);
        af[mf] = *(const bf16x8*)((const char*)As + r * 128 + c * 16);
      }
      #pragma unroll
      for (int nf = 0; nf < 4; ++nf) {
        const int n = wn * 64 + nf * 16 + lr;
        const int c = (ks * 4 + kc) ^ (n & 7);
        bfr[nf] = *(const bf16x8*)((const char*)Bs + n * 128 + c * 16);
      }
      #pragma unroll
      for (int mf = 0; mf < 4; ++mf)
        #pragma unroll
        for (int nf = 0; nf < 4; ++nf)
          acc[mf][nf] = __builtin_amdgcn_mfma_f32_16x16x32_bf16(af[mf], bfr[nf], acc[mf][nf], 0, 0, 0);
    }
    __syncthreads();   // all waves done reading before next stage overwrites
  }

  if (MODE == 0) {
    // cols are interleaved: even = h (w1), odd = g (w3). out col = global_col/2.
    const int fbase = (n0 >> 1) + wn * 32;
    #pragma unroll
    for (int mf = 0; mf < 4; ++mf) {
      const int row = m0 + wm * 64 + mf * 16 + (kc << 2);
      #pragma unroll
      for (int nf = 0; nf < 4; ++nf)
        #pragma unroll
        for (int rr = 0; rr < 4; ++rr) {
          const float v = acc[mf][nf][rr];
          const float o = __shfl_xor(v, 1, 64);
          const float h = (l & 1) ? o : v;
          const float g = (l & 1) ? v : o;
          const float res = (h / (1.f + __expf(-h))) * g;
          const float vc = __shfl(res, (l & 48) | ((l & 7) << 1), 64);
          if (lr < 8)
            hid[(size_t)(row + rr) * FDIM + fbase + nf * 8 + (l & 7)] = f2b(vc);
        }
    }
  } else {
    #pragma unroll
    for (int mf = 0; mf < 4; ++mf) {
      const int row = m0 + wm * 64 + mf * 16 + (kc << 2);
      #pragma unroll
      for (int rr = 0; rr < 4; ++rr) {
        const int tok = rtok[row + rr];
        if (tok < 0) continue;
        const float gwt = rgw[row + rr];
        float* orow = out + (size_t)tok * DDIM;
        #pragma unroll
        for (int nf = 0; nf < 4; ++nf) {
          const int col = n0 + wn * 64 + nf * 16 + lr;
          atomicAdd(orow + col, gwt * acc[mf][nf][rr]);
        }
      }
    }
  }
}

// ---------------- launch ----------------
// ws layout (bytes)
#define OFF_CNT   0u
#define OFF_BASE  64u
#define OFF_SELE  4096u
#define OFF_SELW  36864u
#define OFF_RTOK  69632u
#define OFF_RGW   106496u
#define OFF_XC    1048576u      // 9216*2048 bf16 = 37748736
#define OFF_HID   38797312u     // 9216*4096 bf16 = 75497472
#define OFF_WBUF  114294784u    // 8*8192*2048 bf16 = 268435456 -> end ~365 MB

extern "C" void kernel_launch(void* const* d_in, const int* in_sizes, int n_in,
                              void* d_out, int out_size, void* d_ws, size_t ws_size,
                              hipStream_t stream) {
  const float* x  = (const float*)d_in[0];
  const float* gw = (const float*)d_in[1];
  const float* w1 = (const float*)d_in[2];
  const float* w3 = (const float*)d_in[3];
  const float* w2 = (const float*)d_in[4];
  float* out = (float*)d_out;
  char* ws = (char*)d_ws;

  int*   cnt   = (int*)(ws + OFF_CNT);
  int*   base  = (int*)(ws + OFF_BASE);
  int*   sel_e = (int*)(ws + OFF_SELE);
  float* sel_w = (float*)(ws + OFF_SELW);
  int*   rtok  = (int*)(ws + OFF_RTOK);
  float* rgw   = (float*)(ws + OFF_RGW);
  unsigned short* xc   = (unsigned short*)(ws + OFF_XC);
  unsigned short* hid  = (unsigned short*)(ws + OFF_HID);
  unsigned short* wbuf = (unsigned short*)(ws + OFF_WBUF);

  hipMemsetAsync(d_out, 0, (size_t)T_TOK * DDIM * sizeof(float), stream);
  gate_topk<<<T_TOK / 4, 256, 0, stream>>>(x, gw, sel_e, sel_w);
  build_lists<<<1, 256, 0, stream>>>(sel_e, sel_w, cnt, base, rtok, rgw);
  gather_x<<<MAXROWS, 256, 0, stream>>>(x, base, rtok, xc);
  // w13t[e][8192][2048]: even rows = w1 cols, odd rows = w3 cols
  conv_t<<<dim3(32, 64, 8), 256, 0, stream>>>(w1, wbuf, DDIM, FDIM, 2, 0);
  conv_t<<<dim3(32, 64, 8), 256, 0, stream>>>(w3, wbuf, DDIM, FDIM, 2, 1);
  // 1D grids, %8==0: gemm1 72*64=4608, gemm2 72*16=1152
  moe_gemm<0><<<MAXMT * 64, 256, 0, stream>>>(xc, wbuf, base, rtok, rgw, hid, nullptr);
  // reuse wbuf for w2t[e][2048][4096]
  conv_t<<<dim3(64, 32, 8), 256, 0, stream>>>(w2, wbuf, FDIM, DDIM, 1, 0);
  moe_gemm<1><<<MAXMT * 16, 256, 0, stream>>>(hid, wbuf, base, rtok, rgw, nullptr, out);
}